// Round 4
// baseline (14949.181 us; speedup 1.0000x reference)
//
#include <hip/hip_runtime.h>
#include <hip/hip_bf16.h>

// StackedMatchLSTM on MI355X — multi-CU scan, tag-based LLC sync.
// B=32, TP=512, TQ=64, DP=DQ=H=AH=256, NL=2.
// Scan: 256 WGs = 8 slices x 32 batches. WG (b,j) owns 32 att cols + 128 gate
// cols. Per step: h-wait (tag poll) -> att GEMV -> publish score partials ->
// gate GEMV (hides score flight) -> poll score tags -> softmax -> pre -> gates
// -> publish h slice. All cross-WG data via agent-scope (LLC) load/store with
// release/acquire tags; monotone tag values -> one memset per launch.

#define NB 32
#define TPL 512
#define TQL 64
#define DD 256      // DP = DQ = H = AH
#define H4 1024     // 4*H
#define NC 1280     // AH + 4H
#define NS 8        // slices per batch
#define SC 160      // cols per slice = 32 att + 128 gate

__device__ __forceinline__ float fast_tanh(float x) {
  float xc = fminf(fmaxf(x, -9.f), 9.f);
  float e = __expf(2.f * xc);
  return (e - 1.f) * __builtin_amdgcn_rcpf(e + 1.f);
}
__device__ __forceinline__ float fast_sigmoid(float x) {
  return __builtin_amdgcn_rcpf(1.f + __expf(-x));
}
__device__ __forceinline__ float bflo(unsigned int w) { return __uint_as_float(w << 16); }
__device__ __forceinline__ float bfhi(unsigned int w) { return __uint_as_float(w & 0xffff0000u); }
__device__ __forceinline__ unsigned int packbf(float a, float b) {
  unsigned int lo = __hip_bfloat16_raw(__float2bfloat16(a)).x;
  unsigned int hi = __hip_bfloat16_raw(__float2bfloat16(b)).x;
  return lo | (hi << 16);
}

// ---- agent-scope (cross-XCD coherent, at LLC) helpers -----------------------
__device__ __forceinline__ float aloadf(const float* p) {
  return __hip_atomic_load(p, __ATOMIC_RELAXED, __HIP_MEMORY_SCOPE_AGENT);
}
__device__ __forceinline__ void astoref(float* p, float v) {
  __hip_atomic_store(p, v, __ATOMIC_RELAXED, __HIP_MEMORY_SCOPE_AGENT);
}
__device__ __forceinline__ void tag_release(int* p, int v) {
  __hip_atomic_store(p, v, __ATOMIC_RELEASE, __HIP_MEMORY_SCOPE_AGENT);
}
__device__ __forceinline__ void tag_poll(const int* p, int tgt) {
  int guard = 0;
  while (__hip_atomic_load(p, __ATOMIC_ACQUIRE, __HIP_MEMORY_SCOPE_AGENT) < tgt) {
    __builtin_amdgcn_s_sleep(1);
    if (++guard > (1 << 26)) break;   // bail instead of hanging the harness
  }
}

// permuted xpl column layout: slice-major, per slice: 32 att | f32 | i32 | o32 | g32
__device__ __forceinline__ int perm_col(int c) {
  if (c < DD) return (c >> 5) * SC + (c & 31);
  int cc = c - DD;
  int g = cc >> 8;
  int m = cc & 255;
  return (m >> 5) * SC + 32 + (g << 5) + (m & 31);
}

// ---- weight prep ------------------------------------------------------------
__global__ __launch_bounds__(256) void pack_weights(
    const float* __restrict__ Wp, const float* __restrict__ Wq,
    const float* __restrict__ Wl,
    float* __restrict__ wx, float* __restrict__ wqv)
{
  int d = blockIdx.y;
  int idx = blockIdx.x * 256 + threadIdx.x;
  if (idx >= DD * NC) return;
  int k = idx / NC, j = idx % NC;
  int o = d * DD * NC + idx;
  const float* Wld = Wl + (size_t)d * 768 * H4;
  if (j < DD) {
    int s = d * DD * DD + k * DD + j;
    wx[o] = Wp[s]; wqv[o] = Wq[s];
  } else {
    int c = j - DD;
    wx[o]  = Wld[(size_t)k * H4 + c];
    wqv[o] = Wld[(size_t)(DD + k) * H4 + c];
  }
}

// whs4: bf16 slices, uint4 per (d,j,kq2,pos) = 8 consecutive k of one column.
// flat: ((d*8 + j)*32 + kq2)*160 + pos
__global__ __launch_bounds__(256) void pack_whs(
    const float* __restrict__ Wr, const float* __restrict__ Wl,
    uint4* __restrict__ whs4)
{
  int idx = blockIdx.x * 256 + threadIdx.x;
  if (idx >= 2 * NS * 32 * SC) return;
  int pos = idx % SC; int r = idx / SC;
  int kq2 = r % 32; r /= 32;
  int j = r % NS; int d = r / NS;
  float v[8];
  #pragma unroll
  for (int kr = 0; kr < 8; ++kr) {
    int k = kq2 * 8 + kr;
    float x;
    if (pos < 32) {
      x = Wr[((size_t)d * DD + k) * DD + j * 32 + pos];
    } else {
      int p = pos - 32; int g = p >> 5; int m = j * 32 + (p & 31);
      x = Wl[((size_t)d * 768 + 512 + k) * H4 + (g << 8) + m];
    }
    v[kr] = x;
  }
  whs4[idx] = make_uint4(packbf(v[0], v[1]), packbf(v[2], v[3]),
                         packbf(v[4], v[5]), packbf(v[6], v[7]));
}

// ---- C[M][1280] = A[M][256] @ B[256][1280], fp32 ----------------------------
template <bool PERM>
__global__ __launch_bounds__(256) void sgemm(
    const float* __restrict__ A, const float* __restrict__ Bm,
    float* __restrict__ C)
{
  __shared__ float As[16][65];
  __shared__ float Bs[16][64];
  int tid = threadIdx.x;
  int tx = tid & 15, ty = tid >> 4;
  int col0 = blockIdx.x * 64, row0 = blockIdx.y * 64;
  float acc[4][4] = {};
  for (int kt = 0; kt < DD; kt += 16) {
    #pragma unroll
    for (int i = 0; i < 4; ++i) {
      int e = tid + i * 256;
      As[e & 15][e >> 4] = A[(size_t)(row0 + (e >> 4)) * DD + kt + (e & 15)];
      Bs[e >> 6][e & 63] = Bm[(size_t)(kt + (e >> 6)) * NC + col0 + (e & 63)];
    }
    __syncthreads();
    #pragma unroll
    for (int kk = 0; kk < 16; ++kk) {
      float a[4], bv[4];
      #pragma unroll
      for (int i = 0; i < 4; ++i) a[i] = As[kk][ty * 4 + i];
      #pragma unroll
      for (int jj = 0; jj < 4; ++jj) bv[jj] = Bs[kk][tx * 4 + jj];
      #pragma unroll
      for (int i = 0; i < 4; ++i)
        #pragma unroll
        for (int jj = 0; jj < 4; ++jj)
          acc[i][jj] = fmaf(a[i], bv[jj], acc[i][jj]);
    }
    __syncthreads();
  }
  #pragma unroll
  for (int i = 0; i < 4; ++i)
    #pragma unroll
    for (int jj = 0; jj < 4; ++jj) {
      int c = col0 + tx * 4 + jj;
      int cc = PERM ? perm_col(c) : c;
      C[(size_t)(row0 + ty * 4 + i) * NC + cc] = acc[i][jj];
    }
}

// ---- scan: 256 WGs x 256 threads --------------------------------------------
__global__ __launch_bounds__(256, 1) void scan(
    const float* __restrict__ xpl,    // [NB*TP][NC] permuted cols
    const float* __restrict__ qv,     // [NB*TQ][NC] plain (this layer)
    const uint4* __restrict__ whs4,   // this layer's 8 slices
    const float* __restrict__ wa,
    const float* __restrict__ bias_f,
    const float* __restrict__ bias_iog,
    const float* __restrict__ mask_p,
    const float* __restrict__ mask_q,
    float* __restrict__ xch_s,        // [NB][NS][64]
    float* __restrict__ xch_h,        // [NB][256]
    int* __restrict__ tag_s,          // [NB][NS]
    int* __restrict__ tag_h,          // [NB][NS]
    float* __restrict__ out,          // [NB*TP][256]
    int tag_base)                     // layer*TPL
{
  const int bid = blockIdx.x;
  const int j = bid & 7, b = bid >> 3;
  const int tid = threadIdx.x;

  __shared__ __align__(16) float h_lds[DD];
  __shared__ float xsl_s[SC];
  __shared__ float hw_att_s[32], wa_sh[32], c_sh[32];
  __shared__ float qWq_lds[TQL][33];
  __shared__ float Vl_lds[TQL][128];
  __shared__ float sc_part[4][TQL];
  __shared__ float al_s[TQL];
  __shared__ float pre_s[128], bias_sh[128];

  const float* qv_b = qv + (size_t)b * TQL * NC;
  const uint4* wsl4 = whs4 + (size_t)j * 32 * SC;
  float* xch_s_b = xch_s + b * (NS * TQL);
  float* xch_h_b = xch_h + b * DD;

  // ---- init LDS-resident per-(b,j) data
  for (int i = tid; i < TQL * 32; i += 256) {
    int tq = i >> 5, a = i & 31;
    qWq_lds[tq][a] = qv_b[(size_t)tq * NC + (j << 5) + a];
  }
  for (int i = tid; i < TQL * 128; i += 256) {
    int tq = i >> 7, p = i & 127;
    int g = p >> 5, m = (j << 5) + (p & 31);
    Vl_lds[tq][p] = qv_b[(size_t)tq * NC + DD + (g << 8) + m];
  }
  if (tid < 32) { wa_sh[tid] = wa[(j << 5) + tid]; c_sh[tid] = 0.f; }
  if (tid >= 32 && tid < SC) {
    int p = tid - 32; int g = p >> 5; int m = (j << 5) + (p & 31);
    bias_sh[p] = (g == 0) ? bias_f[m] : bias_iog[((g - 1) << 8) + m];
  }
  float mq = (tid < TQL) ? mask_q[b * TQL + tid] : 0.f;
  __syncthreads();

  const int gcol = tid >> 1, ghalf = tid & 1;

  for (int t = 0; t < TPL; ++t) {
    const float* xs = xpl + ((size_t)b * TPL + t) * NC + j * SC;
    float xv = (tid < SC) ? xs[tid] : 0.f;        // in flight during h-poll
    float mtv = mask_p[b * TPL + t];

    // ---- wait for h[t] (parallel tag poll, lanes 0..7), gather to LDS
    if (t > 0) {
      if (tid < NS) tag_poll(&tag_h[b * NS + tid], tag_base + t);
      __syncthreads();
      h_lds[tid] = aloadf(xch_h_b + tid);
    } else {
      h_lds[tid] = 0.f;
    }
    if (tid < SC) xsl_s[tid] = xv;
    __syncthreads();                               // B1: h_lds + xsl ready

    // ---- att GEMV: 32 cols, k split 4-way (threads 0..127)
    if (tid < 128) {
      int col = tid >> 2, q = tid & 3;
      float a0 = 0.f;
      #pragma unroll
      for (int i = 0; i < 8; ++i) {
        int kq2 = q * 8 + i;
        uint4 w = wsl4[kq2 * SC + col];
        float4 h0 = *(const float4*)&h_lds[kq2 * 8];
        float4 h1 = *(const float4*)&h_lds[kq2 * 8 + 4];
        a0 = fmaf(h0.x, bflo(w.x), a0); a0 = fmaf(h0.y, bfhi(w.x), a0);
        a0 = fmaf(h0.z, bflo(w.y), a0); a0 = fmaf(h0.w, bfhi(w.y), a0);
        a0 = fmaf(h1.x, bflo(w.z), a0); a0 = fmaf(h1.y, bfhi(w.z), a0);
        a0 = fmaf(h1.z, bflo(w.w), a0); a0 = fmaf(h1.w, bfhi(w.w), a0);
      }
      a0 += __shfl_xor(a0, 1);
      a0 += __shfl_xor(a0, 2);
      if (q == 0) hw_att_s[col] = a0;
    }
    __syncthreads();                               // B2a: hw_att ready

    // ---- scores: 64 tq x 32 own cols, 4-way col split
    {
      int tq = tid & 63, sub = tid >> 6;
      float part = 0.f;
      #pragma unroll
      for (int i = 0; i < 8; ++i) {
        int a = sub * 8 + i;
        part = fmaf(fast_tanh(qWq_lds[tq][a] + xsl_s[a] + hw_att_s[a]),
                    wa_sh[a], part);
      }
      sc_part[sub][tq] = part;
    }
    __syncthreads();                               // B2b
    if (tid < TQL) {
      float sp = sc_part[0][tid] + sc_part[1][tid] + sc_part[2][tid] + sc_part[3][tid];
      astoref(xch_s_b + j * TQL + tid, sp);
    }
    if (tid == 0) tag_release(&tag_s[b * NS + j], tag_base + t + 1);
    // (score stores + tag all from wave 0; release drains wave-0 vmcnt)

    // ---- gate GEMV: 128 cols, k split 2-way (all 256 threads) — hides score flight
    float hw_g = 0.f;
    {
      #pragma unroll
      for (int i = 0; i < 16; ++i) {
        int kq2 = ghalf * 16 + i;
        uint4 w = wsl4[kq2 * SC + 32 + gcol];
        float4 h0 = *(const float4*)&h_lds[kq2 * 8];
        float4 h1 = *(const float4*)&h_lds[kq2 * 8 + 4];
        hw_g = fmaf(h0.x, bflo(w.x), hw_g); hw_g = fmaf(h0.y, bfhi(w.x), hw_g);
        hw_g = fmaf(h0.z, bflo(w.y), hw_g); hw_g = fmaf(h0.w, bfhi(w.y), hw_g);
        hw_g = fmaf(h1.x, bflo(w.z), hw_g); hw_g = fmaf(h1.y, bfhi(w.z), hw_g);
        hw_g = fmaf(h1.z, bflo(w.w), hw_g); hw_g = fmaf(h1.w, bfhi(w.w), hw_g);
      }
      hw_g += __shfl_xor(hw_g, 1);                 // both lanes: full hw_gate[gcol]
    }

    // ---- poll score tags (lanes 0..7), gather + softmax (wave 0)
    if (tid < NS) tag_poll(&tag_s[b * NS + tid], tag_base + t + 1);
    if (tid < TQL) {
      float tot = 0.f;
      #pragma unroll
      for (int q2 = 0; q2 < NS; ++q2) tot += aloadf(xch_s_b + q2 * TQL + tid);
      float v = (mq > 0.f) ? tot : -1e9f;
      float m = v;
      #pragma unroll
      for (int off = 32; off > 0; off >>= 1) m = fmaxf(m, __shfl_xor(m, off));
      float p = __expf(v - m);
      float su = p;
      #pragma unroll
      for (int off = 32; off > 0; off >>= 1) su += __shfl_xor(su, off);
      al_s[tid] = p * __builtin_amdgcn_rcpf(su);
    }
    __syncthreads();                               // B3: al_s ready

    // ---- pre: alpha@Vl (tq split 2-way) + hw_g + x + bias
    {
      float dot = 0.f;
      #pragma unroll
      for (int i = 0; i < 32; ++i) {
        int tq = ghalf * 32 + i;
        dot = fmaf(al_s[tq], Vl_lds[tq][gcol], dot);
      }
      dot += __shfl_xor(dot, 1);
      if (ghalf == 0)
        pre_s[gcol] = hw_g + xsl_s[32 + gcol] + bias_sh[gcol] + dot;
    }
    __syncthreads();                               // B4: pre ready

    // ---- gates + state for own 32 h-elems (threads 0..31, wave 0)
    if (tid < 32) {
      float f  = pre_s[tid];
      float ii = pre_s[32 + tid];
      float oo = pre_s[64 + tid];
      float g  = pre_s[96 + tid];
      int m = (j << 5) + tid;
      float c0 = c_sh[tid], h0 = h_lds[m];
      float c1 = fast_sigmoid(f) * c0 + fast_sigmoid(ii) * fast_tanh(g);
      c1 = c1 * mtv + c0 * (1.f - mtv);
      float h1 = fast_sigmoid(oo) * fast_tanh(c1);
      h1 = h1 * mtv + h0 * (1.f - mtv);
      c_sh[tid] = c1;
      astoref(xch_h_b + m, h1);
      out[((size_t)b * TPL + t) * DD + m] = h1;
    }
    if (tid == 0) tag_release(&tag_h[b * NS + j], tag_base + t + 1);
    // no trailing barrier: next iteration's post-poll barrier protects h_lds
  }
}

// -----------------------------------------------------------------------------
extern "C" void kernel_launch(void* const* d_in, const int* in_sizes, int n_in,
                              void* d_out, int out_size, void* d_ws, size_t ws_size,
                              hipStream_t stream) {
  const float* input_p  = (const float*)d_in[0];
  const float* mask_p   = (const float*)d_in[1];
  const float* input_q  = (const float*)d_in[2];
  const float* mask_q   = (const float*)d_in[3];
  const float* W_att_p  = (const float*)d_in[4];
  const float* W_att_q  = (const float*)d_in[5];
  const float* W_att_r  = (const float*)d_in[6];
  const float* w_att    = (const float*)d_in[7];
  const float* W_lstm   = (const float*)d_in[8];
  const float* bias_f   = (const float*)d_in[9];
  const float* bias_iog = (const float*)d_in[10];
  float* out = (float*)d_out;
  float* ws  = (float*)d_ws;
  (void)ws_size; (void)in_sizes; (void)n_in; (void)out_size;

  const size_t SZ_XPL = (size_t)NB * TPL * NC;
  const size_t SZ_QV  = (size_t)NB * TQL * NC;
  const size_t SZ_W   = (size_t)DD * NC;
  const size_t SZ_WHS = (size_t)NS * 32 * SC;      // uint4 per layer

  float* ws_xpl = ws;
  float* ws_qv  = ws_xpl + SZ_XPL;
  float* ws_wx  = ws_qv  + 2 * SZ_QV;
  float* ws_wqv = ws_wx  + 2 * SZ_W;
  float* ws_o0  = ws_wqv + 2 * SZ_W;
  uint4* ws_whs = (uint4*)(ws_o0 + (size_t)NB * TPL * DD);
  float* ws_xs  = (float*)(ws_whs + 2 * SZ_WHS);   // xch_s [NB][8][64]
  float* ws_xh  = ws_xs + NB * NS * TQL;           // xch_h [NB][256]
  int*   ws_tag = (int*)(ws_xh + NB * DD);         // [2][NB][NS]: tag_s, tag_h
  int*   tag_s  = ws_tag;
  int*   tag_h  = ws_tag + NB * NS;

  dim3 gpack((DD * NC + 255) / 256, 2);
  pack_weights<<<gpack, 256, 0, stream>>>(W_att_p, W_att_q, W_lstm, ws_wx, ws_wqv);
  pack_whs<<<(2 * NS * 32 * SC + 255) / 256, 256, 0, stream>>>(W_att_r, W_lstm, ws_whs);
  hipMemsetAsync(ws_tag, 0, 2 * NB * NS * sizeof(int), stream);

  for (int d = 0; d < 2; ++d) {
    dim3 g(NC / 64, (NB * TQL) / 64);
    sgemm<false><<<g, 256, 0, stream>>>(input_q, ws_wqv + d * SZ_W, ws_qv + d * SZ_QV);
  }

  // layer 0
  {
    dim3 g(NC / 64, (NB * TPL) / 64);
    sgemm<true><<<g, 256, 0, stream>>>(input_p, ws_wx, ws_xpl);
    scan<<<NB * NS, 256, 0, stream>>>(ws_xpl, ws_qv, ws_whs,
                                      w_att, bias_f, bias_iog, mask_p, mask_q,
                                      ws_xs, ws_xh, tag_s, tag_h, ws_o0, 0);
  }
  // layer 1
  {
    dim3 g(NC / 64, (NB * TPL) / 64);
    sgemm<true><<<g, 256, 0, stream>>>(ws_o0, ws_wx + SZ_W, ws_xpl);
    scan<<<NB * NS, 256, 0, stream>>>(ws_xpl, ws_qv + SZ_QV, ws_whs + SZ_WHS,
                                      w_att + DD, bias_f + DD, bias_iog + 3 * DD,
                                      mask_p, mask_q, ws_xs, ws_xh, tag_s, tag_h,
                                      out, TPL);
  }
}

// Round 5
// 13741.412 us; speedup vs baseline: 1.0879x; 1.0879x over previous
//
#include <hip/hip_runtime.h>
#include <hip/hip_bf16.h>

// StackedMatchLSTM on MI355X — multi-CU scan, attention replicated, 1 sync/step.
// B=32, TP=512, TQ=64, DP=DQ=H=AH=256, NL=2.
// Scan: 256 WGs = 8 slices x 32 batches. Every WG computes the FULL attention
// (hw_att 256 cols, scores, softmax) locally; owns 128 gate cols (f,i,o,g x 32
// h-elems). Only cross-WG exchange per step: h (256 f) via relaxed sc1 stores
// + per-slice RMW tag (release add / relaxed add-0 spin) — round-3-proven
// stable primitive; no acquire/release cacheline protocol (no L2 inv storms).

#define NB 32
#define TPL 512
#define TQL 64
#define DD 256      // DP = DQ = H = AH
#define H4 1024     // 4*H
#define NC 1280     // AH + 4H
#define NS 8        // slices per batch
#define GC 128      // gate cols per slice

__device__ __forceinline__ float fast_tanh(float x) {
  float xc = fminf(fmaxf(x, -9.f), 9.f);
  float e = __expf(2.f * xc);
  return (e - 1.f) * __builtin_amdgcn_rcpf(e + 1.f);
}
__device__ __forceinline__ float fast_sigmoid(float x) {
  return __builtin_amdgcn_rcpf(1.f + __expf(-x));
}
__device__ __forceinline__ float bflo(unsigned int w) { return __uint_as_float(w << 16); }
__device__ __forceinline__ float bfhi(unsigned int w) { return __uint_as_float(w & 0xffff0000u); }
__device__ __forceinline__ unsigned int packbf(float a, float b) {
  unsigned int lo = __hip_bfloat16_raw(__float2bfloat16(a)).x;
  unsigned int hi = __hip_bfloat16_raw(__float2bfloat16(b)).x;
  return lo | (hi << 16);
}

// ---- agent-scope sync: RMW-only (executes at LLC, stale-proof) --------------
__device__ __forceinline__ float aloadf(const float* p) {
  return __hip_atomic_load(p, __ATOMIC_RELAXED, __HIP_MEMORY_SCOPE_AGENT);
}
__device__ __forceinline__ void astoref(float* p, float v) {
  __hip_atomic_store(p, v, __ATOMIC_RELAXED, __HIP_MEMORY_SCOPE_AGENT);
}
__device__ __forceinline__ void radd(int* p) {
  __hip_atomic_fetch_add(p, 1, __ATOMIC_RELEASE, __HIP_MEMORY_SCOPE_AGENT);
}
__device__ __forceinline__ void spin_ge(int* p, int tgt) {
  int guard = 0;
  while (__hip_atomic_fetch_add(p, 0, __ATOMIC_RELAXED, __HIP_MEMORY_SCOPE_AGENT) < tgt) {
    __builtin_amdgcn_s_sleep(1);
    if (++guard > (1 << 26)) break;   // bail instead of hanging the harness
  }
}

// permuted xpl cols: [0,256) att (shared) | per slice j: 128 gate cols f|i|o|g
__device__ __forceinline__ int perm_col(int c) {
  if (c < DD) return c;
  int cc = c - DD;
  int g = cc >> 8;          // 0..3 = f,i,o,g
  int m = cc & 255;         // h-elem
  return DD + (m >> 5) * GC + (g << 5) + (m & 31);
}

// ---- weight prep ------------------------------------------------------------
__global__ __launch_bounds__(256) void pack_weights(
    const float* __restrict__ Wp, const float* __restrict__ Wq,
    const float* __restrict__ Wl,
    float* __restrict__ wx, float* __restrict__ wqv)
{
  int d = blockIdx.y;
  int idx = blockIdx.x * 256 + threadIdx.x;
  if (idx >= DD * NC) return;
  int k = idx / NC, j = idx % NC;
  int o = d * DD * NC + idx;
  const float* Wld = Wl + (size_t)d * 768 * H4;
  if (j < DD) {
    int s = d * DD * DD + k * DD + j;
    wx[o] = Wp[s]; wqv[o] = Wq[s];
  } else {
    int c = j - DD;
    wx[o]  = Wld[(size_t)k * H4 + c];
    wqv[o] = Wld[(size_t)(DD + k) * H4 + c];
  }
}

// whatt4[d][kq2(32)][col(256)]: uint4 = 8 consecutive k of W_att_r[d][k][col]
__global__ __launch_bounds__(256) void pack_whatt(
    const float* __restrict__ Wr, uint4* __restrict__ whatt4)
{
  int idx = blockIdx.x * 256 + threadIdx.x;     // 2*32*256
  if (idx >= 2 * 32 * 256) return;
  int col = idx & 255; int r = idx >> 8;
  int kq2 = r & 31; int d = r >> 5;
  float v[8];
  #pragma unroll
  for (int kr = 0; kr < 8; ++kr)
    v[kr] = Wr[((size_t)d * DD + kq2 * 8 + kr) * DD + col];
  whatt4[idx] = make_uint4(packbf(v[0], v[1]), packbf(v[2], v[3]),
                           packbf(v[4], v[5]), packbf(v[6], v[7]));
}

// whg4[d][j(8)][kq2(32)][gcol(128)]: uint4 = 8 k of Wl h-part col (g,j,pos)
__global__ __launch_bounds__(256) void pack_whg(
    const float* __restrict__ Wl, uint4* __restrict__ whg4)
{
  int idx = blockIdx.x * 256 + threadIdx.x;     // 2*8*32*128
  if (idx >= 2 * NS * 32 * GC) return;
  int gcol = idx & 127; int r = idx >> 7;
  int kq2 = r & 31; r >>= 5;
  int j = r & 7; int d = r >> 3;
  int g = gcol >> 5, pos = gcol & 31;
  float v[8];
  #pragma unroll
  for (int kr = 0; kr < 8; ++kr) {
    int k = kq2 * 8 + kr;
    v[kr] = Wl[((size_t)d * 768 + 512 + k) * H4 + (g << 8) + (j << 5) + pos];
  }
  whg4[idx] = make_uint4(packbf(v[0], v[1]), packbf(v[2], v[3]),
                         packbf(v[4], v[5]), packbf(v[6], v[7]));
}

// ---- C[M][1280] = A[M][256] @ B[256][1280], fp32 ----------------------------
template <bool PERM>
__global__ __launch_bounds__(256) void sgemm(
    const float* __restrict__ A, const float* __restrict__ Bm,
    float* __restrict__ C)
{
  __shared__ float As[16][65];
  __shared__ float Bs[16][64];
  int tid = threadIdx.x;
  int tx = tid & 15, ty = tid >> 4;
  int col0 = blockIdx.x * 64, row0 = blockIdx.y * 64;
  float acc[4][4] = {};
  for (int kt = 0; kt < DD; kt += 16) {
    #pragma unroll
    for (int i = 0; i < 4; ++i) {
      int e = tid + i * 256;
      As[e & 15][e >> 4] = A[(size_t)(row0 + (e >> 4)) * DD + kt + (e & 15)];
      Bs[e >> 6][e & 63] = Bm[(size_t)(kt + (e >> 6)) * NC + col0 + (e & 63)];
    }
    __syncthreads();
    #pragma unroll
    for (int kk = 0; kk < 16; ++kk) {
      float a[4], bv[4];
      #pragma unroll
      for (int i = 0; i < 4; ++i) a[i] = As[kk][ty * 4 + i];
      #pragma unroll
      for (int jj = 0; jj < 4; ++jj) bv[jj] = Bs[kk][tx * 4 + jj];
      #pragma unroll
      for (int i = 0; i < 4; ++i)
        #pragma unroll
        for (int jj = 0; jj < 4; ++jj)
          acc[i][jj] = fmaf(a[i], bv[jj], acc[i][jj]);
    }
    __syncthreads();
  }
  #pragma unroll
  for (int i = 0; i < 4; ++i)
    #pragma unroll
    for (int jj = 0; jj < 4; ++jj) {
      int c = col0 + tx * 4 + jj;
      int cc = PERM ? perm_col(c) : c;
      C[(size_t)(row0 + ty * 4 + i) * NC + cc] = acc[i][jj];
    }
}

// ---- scan: 256 WGs x 256 threads --------------------------------------------
__global__ __launch_bounds__(256, 1) void scan(
    const float* __restrict__ xpl,    // [NB*TP][NC] permuted cols
    const float* __restrict__ qv,     // [NB*TQ][NC] plain (this layer)
    const uint4* __restrict__ whatt,  // [32][256] this layer
    const uint4* __restrict__ whg,    // [8][32][128] this layer
    const float* __restrict__ wa,     // [256]
    const float* __restrict__ bias_f,
    const float* __restrict__ bias_iog,
    const float* __restrict__ mask_p,
    const float* __restrict__ mask_q,
    float* __restrict__ xch_h,        // [NB][256]
    int* __restrict__ tag_h,          // [NB][NS]
    float* __restrict__ out,          // [NB*TP][256]
    int lbase)                        // layer*TPL
{
  const int bid = blockIdx.x;
  const int j = bid & 7, b = bid >> 3;
  const int tid = threadIdx.x;

  __shared__ __align__(16) float h_lds[DD];
  __shared__ float xa_s[DD], xg_s[GC];
  __shared__ float hw_att_s[DD], wa_s[DD];
  __shared__ float qWq_lds[TQL][257];   // stride 257: conflict-free row-per-lane
  __shared__ float Vl_lds[TQL][GC];
  __shared__ float sc_part[4][TQL];
  __shared__ float al_s[TQL];
  __shared__ float pre_s[GC], bias_s[GC], c_sh[32];

  const float* qv_b = qv + (size_t)b * TQL * NC;
  const uint4* wg_sl = whg + (size_t)j * 32 * GC;
  float* xch_h_b = xch_h + b * DD;

  // ---- init LDS
  for (int i = tid; i < TQL * DD; i += 256) {
    int tq = i >> 8, a = i & 255;
    qWq_lds[tq][a] = qv_b[(size_t)tq * NC + a];
  }
  for (int i = tid; i < TQL * GC; i += 256) {
    int tq = i >> 7, p = i & 127;
    int g = p >> 5, m = (j << 5) + (p & 31);
    Vl_lds[tq][p] = qv_b[(size_t)tq * NC + DD + (g << 8) + m];
  }
  wa_s[tid] = wa[tid];
  if (tid < GC) {
    int g = tid >> 5, m = (j << 5) + (tid & 31);
    bias_s[tid] = (g == 0) ? bias_f[m] : bias_iog[((g - 1) << 8) + m];
  }
  if (tid < 32) c_sh[tid] = 0.f;
  float mq = (tid < TQL) ? mask_q[b * TQL + tid] : 0.f;
  __syncthreads();

  const int gcol = tid >> 1, ghalf = tid & 1;

  for (int t = 0; t < TPL; ++t) {
    const float* xrow = xpl + ((size_t)b * TPL + t) * NC;
    float xa = xrow[tid];                                   // att col (in flight)
    float xg = (tid < GC) ? xrow[DD + j * GC + tid] : 0.f;  // own gate col
    float mtv = mask_p[b * TPL + t];

    // ---- wait for h[t] (lanes poll other slices' tags), gather to LDS
    if (t > 0) {
      if (tid < NS && tid != j) spin_ge(&tag_h[b * NS + tid], lbase + t);
    }
    __syncthreads();                       // pollers done; step-(t-1) LDS reads done
    h_lds[tid] = (t > 0) ? aloadf(xch_h_b + tid) : 0.f;
    xa_s[tid] = xa;
    if (tid < GC) xg_s[tid] = xg;
    __syncthreads();                       // B1: h_lds, xa_s, xg_s ready

    // ---- att GEMV (full 256 cols, thread = col): h reads are wave-uniform
    {
      float aw = 0.f;
      const uint4* wp = whatt + tid;
      #pragma unroll 8
      for (int kq2 = 0; kq2 < 32; ++kq2) {
        uint4 w = wp[kq2 * 256];
        float4 h0 = *(const float4*)&h_lds[kq2 * 8];
        float4 h1 = *(const float4*)&h_lds[kq2 * 8 + 4];
        aw = fmaf(h0.x, bflo(w.x), aw); aw = fmaf(h0.y, bfhi(w.x), aw);
        aw = fmaf(h0.z, bflo(w.y), aw); aw = fmaf(h0.w, bfhi(w.y), aw);
        aw = fmaf(h1.x, bflo(w.z), aw); aw = fmaf(h1.y, bfhi(w.z), aw);
        aw = fmaf(h1.z, bflo(w.w), aw); aw = fmaf(h1.w, bfhi(w.w), aw);
      }
      hw_att_s[tid] = aw;
    }
    __syncthreads();                       // B2: hw_att ready

    // ---- gate GEMV (own 128 cols, 2-way k-split) — loads fly under scores
    float hw_g = 0.f;
    {
      const uint4* gp = wg_sl + gcol;
      #pragma unroll
      for (int i = 0; i < 16; ++i) {
        int kq2 = ghalf * 16 + i;
        uint4 w = gp[kq2 * GC];
        float4 h0 = *(const float4*)&h_lds[kq2 * 8];
        float4 h1 = *(const float4*)&h_lds[kq2 * 8 + 4];
        hw_g = fmaf(h0.x, bflo(w.x), hw_g); hw_g = fmaf(h0.y, bfhi(w.x), hw_g);
        hw_g = fmaf(h0.z, bflo(w.y), hw_g); hw_g = fmaf(h0.w, bfhi(w.y), hw_g);
        hw_g = fmaf(h1.x, bflo(w.z), hw_g); hw_g = fmaf(h1.y, bfhi(w.z), hw_g);
        hw_g = fmaf(h1.z, bflo(w.w), hw_g); hw_g = fmaf(h1.w, bfhi(w.w), hw_g);
      }
      hw_g += __shfl_xor(hw_g, 1);         // both lanes hold full hw_gate[gcol]
    }

    // ---- scores (full, replicated): wave w covers a in [64w, 64w+64)
    {
      int l = tid & 63, wv = tid >> 6;
      float part = 0.f;
      #pragma unroll 8
      for (int i = 0; i < 64; ++i) {
        int a = wv * 64 + i;
        part = fmaf(fast_tanh(qWq_lds[l][a] + xa_s[a] + hw_att_s[a]),
                    wa_s[a], part);
      }
      sc_part[wv][l] = part;
    }
    __syncthreads();                       // B3: sc_part ready

    // ---- softmax (wave 0) -> al_s
    if (tid < TQL) {
      float v = sc_part[0][tid] + sc_part[1][tid] + sc_part[2][tid] + sc_part[3][tid];
      v = (mq > 0.f) ? v : -1e9f;
      float m = v;
      #pragma unroll
      for (int off = 32; off > 0; off >>= 1) m = fmaxf(m, __shfl_xor(m, off));
      float p = __expf(v - m);
      float su = p;
      #pragma unroll
      for (int off = 32; off > 0; off >>= 1) su += __shfl_xor(su, off);
      al_s[tid] = p * __builtin_amdgcn_rcpf(su);
    }
    __syncthreads();                       // B4: al_s ready

    // ---- pre: alpha@Vl (2-way tq split) + hw_g + x + bias
    {
      float dot = 0.f;
      #pragma unroll 8
      for (int i = 0; i < 32; ++i) {
        int tq = ghalf * 32 + i;
        dot = fmaf(al_s[tq], Vl_lds[tq][gcol], dot);
      }
      dot += __shfl_xor(dot, 1);
      if (ghalf == 0)
        pre_s[gcol] = hw_g + dot + xg_s[gcol] + bias_s[gcol];
    }
    __syncthreads();                       // B5: pre ready

    // ---- gates + state for own 32 h-elems; publish h slice + tag
    if (tid < 32) {
      float f  = pre_s[tid];
      float ii = pre_s[32 + tid];
      float oo = pre_s[64 + tid];
      float g  = pre_s[96 + tid];
      int m = (j << 5) + tid;
      float c0 = c_sh[tid], h0 = h_lds[m];
      float c1 = fast_sigmoid(f) * c0 + fast_sigmoid(ii) * fast_tanh(g);
      c1 = c1 * mtv + c0 * (1.f - mtv);
      float h1 = fast_sigmoid(oo) * fast_tanh(c1);
      h1 = h1 * mtv + h0 * (1.f - mtv);
      c_sh[tid] = c1;
      astoref(xch_h_b + m, h1);            // sc1 payload, straight to LLC
      if (tid == 0) radd(&tag_h[b * NS + j]);  // RELEASE add: drains wave stores
      out[((size_t)b * TPL + t) * DD + m] = h1;  // non-critical, after release
    }
    // no trailing barrier: next iteration's post-poll barrier orders h_lds reuse
  }
}

// -----------------------------------------------------------------------------
extern "C" void kernel_launch(void* const* d_in, const int* in_sizes, int n_in,
                              void* d_out, int out_size, void* d_ws, size_t ws_size,
                              hipStream_t stream) {
  const float* input_p  = (const float*)d_in[0];
  const float* mask_p   = (const float*)d_in[1];
  const float* input_q  = (const float*)d_in[2];
  const float* mask_q   = (const float*)d_in[3];
  const float* W_att_p  = (const float*)d_in[4];
  const float* W_att_q  = (const float*)d_in[5];
  const float* W_att_r  = (const float*)d_in[6];
  const float* w_att    = (const float*)d_in[7];
  const float* W_lstm   = (const float*)d_in[8];
  const float* bias_f   = (const float*)d_in[9];
  const float* bias_iog = (const float*)d_in[10];
  float* out = (float*)d_out;
  float* ws  = (float*)d_ws;
  (void)ws_size; (void)in_sizes; (void)n_in; (void)out_size;

  const size_t SZ_XPL   = (size_t)NB * TPL * NC;
  const size_t SZ_QV    = (size_t)NB * TQL * NC;
  const size_t SZ_W     = (size_t)DD * NC;
  const size_t SZ_WATT  = (size_t)32 * 256;        // uint4 per layer
  const size_t SZ_WG    = (size_t)NS * 32 * GC;    // uint4 per layer

  float* ws_xpl = ws;
  float* ws_qv  = ws_xpl + SZ_XPL;
  float* ws_wx  = ws_qv  + 2 * SZ_QV;
  float* ws_wqv = ws_wx  + 2 * SZ_W;
  float* ws_o0  = ws_wqv + 2 * SZ_W;
  uint4* ws_watt = (uint4*)(ws_o0 + (size_t)NB * TPL * DD);
  uint4* ws_wg   = ws_watt + 2 * SZ_WATT;
  float* ws_xh   = (float*)(ws_wg + 2 * SZ_WG);    // xch_h [NB][256]
  int*   ws_tag  = (int*)(ws_xh + NB * DD);        // tag_h [NB][NS]

  dim3 gpack((DD * NC + 255) / 256, 2);
  pack_weights<<<gpack, 256, 0, stream>>>(W_att_p, W_att_q, W_lstm, ws_wx, ws_wqv);
  pack_whatt<<<(2 * 32 * 256) / 256, 256, 0, stream>>>(W_att_r, ws_watt);
  pack_whg<<<(2 * NS * 32 * GC) / 256, 256, 0, stream>>>(W_lstm, ws_wg);
  hipMemsetAsync(ws_tag, 0, NB * NS * sizeof(int), stream);

  for (int d = 0; d < 2; ++d) {
    dim3 g(NC / 64, (NB * TQL) / 64);
    sgemm<false><<<g, 256, 0, stream>>>(input_q, ws_wqv + d * SZ_W, ws_qv + d * SZ_QV);
  }

  // layer 0
  {
    dim3 g(NC / 64, (NB * TPL) / 64);
    sgemm<true><<<g, 256, 0, stream>>>(input_p, ws_wx, ws_xpl);
    scan<<<NB * NS, 256, 0, stream>>>(ws_xpl, ws_qv, ws_watt, ws_wg,
                                      w_att, bias_f, bias_iog, mask_p, mask_q,
                                      ws_xh, ws_tag, ws_o0, 0);
  }
  // layer 1
  {
    dim3 g(NC / 64, (NB * TPL) / 64);
    sgemm<true><<<g, 256, 0, stream>>>(ws_o0, ws_wx + SZ_W, ws_xpl);
    scan<<<NB * NS, 256, 0, stream>>>(ws_xpl, ws_qv + SZ_QV, ws_watt + SZ_WATT,
                                      ws_wg + SZ_WG, w_att + DD, bias_f + DD,
                                      bias_iog + 3 * DD, mask_p, mask_q,
                                      ws_xh, ws_tag, out, TPL);
  }
}

// Round 6
// 9566.479 us; speedup vs baseline: 1.5627x; 1.4364x over previous
//
#include <hip/hip_runtime.h>
#include <hip/hip_bf16.h>

// StackedMatchLSTM on MI355X — multi-CU scan, attention replicated, 1 sync/step.
// B=32, TP=512, TQ=64, DP=DQ=H=AH=256, NL=2.
// Scan: 256 WGs (8 slices x 32 batches) x 512 threads. Every WG computes the
// FULL attention locally (replicated); owns 128 gate cols. Cross-WG exchange
// per step: h (256 f) via relaxed agent stores + per-slice RMW tag
// (release-add / relaxed add-0 spin). Phase-parallel GEMVs: waves 0-3 att,
// waves 4-7 gate — two concurrent L2 streams.

#define NB 32
#define TPL 512
#define TQL 64
#define DD 256      // DP = DQ = H = AH
#define H4 1024     // 4*H
#define NC 1280     // AH + 4H
#define NS 8        // slices per batch
#define GC 128      // gate cols per slice
#define TAGSTR 16   // ints between tags (64 B)

__device__ __forceinline__ float fast_tanh(float x) {
  float xc = fminf(fmaxf(x, -9.f), 9.f);
  float e = __expf(2.f * xc);
  return (e - 1.f) * __builtin_amdgcn_rcpf(e + 1.f);
}
__device__ __forceinline__ float fast_sigmoid(float x) {
  return __builtin_amdgcn_rcpf(1.f + __expf(-x));
}
__device__ __forceinline__ float bflo(unsigned int w) { return __uint_as_float(w << 16); }
__device__ __forceinline__ float bfhi(unsigned int w) { return __uint_as_float(w & 0xffff0000u); }
__device__ __forceinline__ unsigned int packbf(float a, float b) {
  unsigned int lo = __hip_bfloat16_raw(__float2bfloat16(a)).x;
  unsigned int hi = __hip_bfloat16_raw(__float2bfloat16(b)).x;
  return lo | (hi << 16);
}

// ---- agent-scope sync: RMW-only (executes at LLC, stale-proof) --------------
__device__ __forceinline__ float aloadf(const float* p) {
  return __hip_atomic_load(p, __ATOMIC_RELAXED, __HIP_MEMORY_SCOPE_AGENT);
}
__device__ __forceinline__ void astoref(float* p, float v) {
  __hip_atomic_store(p, v, __ATOMIC_RELAXED, __HIP_MEMORY_SCOPE_AGENT);
}
__device__ __forceinline__ void radd(int* p) {
  __hip_atomic_fetch_add(p, 1, __ATOMIC_RELEASE, __HIP_MEMORY_SCOPE_AGENT);
}
__device__ __forceinline__ void spin_ge(int* p, int tgt) {
  int guard = 0;
  while (__hip_atomic_fetch_add(p, 0, __ATOMIC_RELAXED, __HIP_MEMORY_SCOPE_AGENT) < tgt) {
    __builtin_amdgcn_s_sleep(1);
    if (++guard > (1 << 26)) break;   // bail instead of hanging the harness
  }
}

// permuted xpl cols: [0,256) att (shared) | per slice j: 128 gate cols f|i|o|g
__device__ __forceinline__ int perm_col(int c) {
  if (c < DD) return c;
  int cc = c - DD;
  int g = cc >> 8;          // 0..3 = f,i,o,g
  int m = cc & 255;         // h-elem
  return DD + (m >> 5) * GC + (g << 5) + (m & 31);
}

// ---- weight prep ------------------------------------------------------------
__global__ __launch_bounds__(256) void pack_weights(
    const float* __restrict__ Wp, const float* __restrict__ Wq,
    const float* __restrict__ Wl,
    float* __restrict__ wx, float* __restrict__ wqv)
{
  int d = blockIdx.y;
  int idx = blockIdx.x * 256 + threadIdx.x;
  if (idx >= DD * NC) return;
  int k = idx / NC, j = idx % NC;
  int o = d * DD * NC + idx;
  const float* Wld = Wl + (size_t)d * 768 * H4;
  if (j < DD) {
    int s = d * DD * DD + k * DD + j;
    wx[o] = Wp[s]; wqv[o] = Wq[s];
  } else {
    int c = j - DD;
    wx[o]  = Wld[(size_t)k * H4 + c];
    wqv[o] = Wld[(size_t)(DD + k) * H4 + c];
  }
}

// whatt4[d][kq2(32)][col(256)]: uint4 = 8 consecutive k of W_att_r[d][k][col]
__global__ __launch_bounds__(256) void pack_whatt(
    const float* __restrict__ Wr, uint4* __restrict__ whatt4)
{
  int idx = blockIdx.x * 256 + threadIdx.x;     // 2*32*256
  if (idx >= 2 * 32 * 256) return;
  int col = idx & 255; int r = idx >> 8;
  int kq2 = r & 31; int d = r >> 5;
  float v[8];
  #pragma unroll
  for (int kr = 0; kr < 8; ++kr)
    v[kr] = Wr[((size_t)d * DD + kq2 * 8 + kr) * DD + col];
  whatt4[idx] = make_uint4(packbf(v[0], v[1]), packbf(v[2], v[3]),
                           packbf(v[4], v[5]), packbf(v[6], v[7]));
}

// whg4[d][j(8)][kq2(32)][gcol(128)]: uint4 = 8 k of Wl h-part col (g,j,pos)
__global__ __launch_bounds__(256) void pack_whg(
    const float* __restrict__ Wl, uint4* __restrict__ whg4)
{
  int idx = blockIdx.x * 256 + threadIdx.x;     // 2*8*32*128
  if (idx >= 2 * NS * 32 * GC) return;
  int gcol = idx & 127; int r = idx >> 7;
  int kq2 = r & 31; r >>= 5;
  int j = r & 7; int d = r >> 3;
  int g = gcol >> 5, pos = gcol & 31;
  float v[8];
  #pragma unroll
  for (int kr = 0; kr < 8; ++kr) {
    int k = kq2 * 8 + kr;
    v[kr] = Wl[((size_t)d * 768 + 512 + k) * H4 + (g << 8) + (j << 5) + pos];
  }
  whg4[idx] = make_uint4(packbf(v[0], v[1]), packbf(v[2], v[3]),
                         packbf(v[4], v[5]), packbf(v[6], v[7]));
}

// ---- C[M][1280] = A[M][256] @ B[256][1280], fp32 ----------------------------
template <bool PERM>
__global__ __launch_bounds__(256) void sgemm(
    const float* __restrict__ A, const float* __restrict__ Bm,
    float* __restrict__ C)
{
  __shared__ float As[16][65];
  __shared__ float Bs[16][64];
  int tid = threadIdx.x;
  int tx = tid & 15, ty = tid >> 4;
  int col0 = blockIdx.x * 64, row0 = blockIdx.y * 64;
  float acc[4][4] = {};
  for (int kt = 0; kt < DD; kt += 16) {
    #pragma unroll
    for (int i = 0; i < 4; ++i) {
      int e = tid + i * 256;
      As[e & 15][e >> 4] = A[(size_t)(row0 + (e >> 4)) * DD + kt + (e & 15)];
      Bs[e >> 6][e & 63] = Bm[(size_t)(kt + (e >> 6)) * NC + col0 + (e & 63)];
    }
    __syncthreads();
    #pragma unroll
    for (int kk = 0; kk < 16; ++kk) {
      float a[4], bv[4];
      #pragma unroll
      for (int i = 0; i < 4; ++i) a[i] = As[kk][ty * 4 + i];
      #pragma unroll
      for (int jj = 0; jj < 4; ++jj) bv[jj] = Bs[kk][tx * 4 + jj];
      #pragma unroll
      for (int i = 0; i < 4; ++i)
        #pragma unroll
        for (int jj = 0; jj < 4; ++jj)
          acc[i][jj] = fmaf(a[i], bv[jj], acc[i][jj]);
    }
    __syncthreads();
  }
  #pragma unroll
  for (int i = 0; i < 4; ++i)
    #pragma unroll
    for (int jj = 0; jj < 4; ++jj) {
      int c = col0 + tx * 4 + jj;
      int cc = PERM ? perm_col(c) : c;
      C[(size_t)(row0 + ty * 4 + i) * NC + cc] = acc[i][jj];
    }
}

// ---- scan: 256 WGs x 512 threads --------------------------------------------
__global__ __launch_bounds__(512, 2) void scan(
    const float* __restrict__ xpl,    // [NB*TP][NC] permuted cols
    const float* __restrict__ qv,     // [NB*TQ][NC] plain (this layer)
    const uint4* __restrict__ whatt,  // [32][256] this layer
    const uint4* __restrict__ whg,    // [8][32][128] this layer
    const float* __restrict__ wa,     // [256]
    const float* __restrict__ bias_f,
    const float* __restrict__ bias_iog,
    const float* __restrict__ mask_p,
    const float* __restrict__ mask_q,
    float* __restrict__ xch_h,        // [NB][256]
    int* __restrict__ tag_h,          // [NB][NS] stride TAGSTR
    float* __restrict__ out,          // [NB*TP][256]
    int lbase)                        // layer*TPL
{
  const int bid = blockIdx.x;
  const int j = bid & 7, b = bid >> 3;
  const int tid = threadIdx.x;

  __shared__ __align__(16) float h_lds[DD];
  __shared__ float xa_s[DD], xg_s[GC];
  __shared__ float hw_att_s[DD], wa_s[DD];
  __shared__ float qWqT[DD][65];        // [a][tq]: wave-uniform row, lane tq
  __shared__ float Vl_lds[TQL][GC];
  __shared__ float sc_part[8][TQL];
  __shared__ float al_s[TQL];
  __shared__ float pre_s[GC], bias_s[GC], c_sh[32];

  const float* qv_b = qv + (size_t)b * TQL * NC;
  const uint4* wg_sl = whg + (size_t)j * 32 * GC;
  float* xch_h_b = xch_h + b * DD;
  int* tags_b = tag_h + b * NS * TAGSTR;

  // ---- init LDS
  for (int i = tid; i < TQL * DD; i += 512) {
    int tq = i >> 8, a = i & 255;       // coalesced read, scattered LDS write
    qWqT[a][tq] = qv_b[(size_t)tq * NC + a];
  }
  for (int i = tid; i < TQL * GC; i += 512) {
    int tq = i >> 7, p = i & 127;
    int g = p >> 5, m = (j << 5) + (p & 31);
    Vl_lds[tq][p] = qv_b[(size_t)tq * NC + DD + (g << 8) + m];
  }
  if (tid < DD) wa_s[tid] = wa[tid];
  if (tid < GC) {
    int g = tid >> 5, m = (j << 5) + (tid & 31);
    bias_s[tid] = (g == 0) ? bias_f[m] : bias_iog[((g - 1) << 8) + m];
  }
  if (tid < 32) c_sh[tid] = 0.f;
  float mq = (tid < TQL) ? mask_q[b * TQL + tid] : 0.f;
  __syncthreads();

  const int local = tid & 255;          // gate-path index for tid>=256
  const int gcol = local >> 1, ghalf = local & 1;

  for (int t = 0; t < TPL; ++t) {
    const float* xrow = xpl + ((size_t)b * TPL + t) * NC;
    float xa = 0.f, xg = 0.f;
    if (tid < DD) xa = xrow[tid];                       // in flight during poll
    else if (tid < DD + GC) xg = xrow[DD + j * GC + (tid - DD)];
    float mtv = mask_p[b * TPL + t];

    // ---- wait for h[t] (lanes poll other slices' tags)
    if (t > 0) {
      if (tid < NS && tid != j) spin_ge(&tags_b[tid * TAGSTR], lbase + t);
    }
    __syncthreads();                    // pollers done; prev-step LDS reads done
    if (tid < DD) {
      h_lds[tid] = (t > 0) ? aloadf(xch_h_b + tid) : 0.f;
      xa_s[tid] = xa;
    } else if (tid < DD + GC) {
      xg_s[tid - DD] = xg;
    }
    __syncthreads();                    // B1: h_lds, xa_s, xg_s ready

    // ---- phase A (parallel streams): waves 0-3 att GEMV, waves 4-7 gate GEMV
    float hw_g = 0.f;
    if (tid < DD) {
      // att: thread = col, full k, 32 uint4
      float aw = 0.f;
      const uint4* wp = whatt + tid;
      #pragma unroll 8
      for (int kq2 = 0; kq2 < 32; ++kq2) {
        uint4 w = wp[kq2 * 256];
        float4 h0 = *(const float4*)&h_lds[kq2 * 8];
        float4 h1 = *(const float4*)&h_lds[kq2 * 8 + 4];
        aw = fmaf(h0.x, bflo(w.x), aw); aw = fmaf(h0.y, bfhi(w.x), aw);
        aw = fmaf(h0.z, bflo(w.y), aw); aw = fmaf(h0.w, bfhi(w.y), aw);
        aw = fmaf(h1.x, bflo(w.z), aw); aw = fmaf(h1.y, bfhi(w.z), aw);
        aw = fmaf(h1.z, bflo(w.w), aw); aw = fmaf(h1.w, bfhi(w.w), aw);
      }
      hw_att_s[tid] = aw;
    } else {
      // gate: 2 threads/col, 16 uint4 each
      const uint4* gp = wg_sl + gcol;
      #pragma unroll 8
      for (int i = 0; i < 16; ++i) {
        int kq2 = ghalf * 16 + i;
        uint4 w = gp[kq2 * GC];
        float4 h0 = *(const float4*)&h_lds[kq2 * 8];
        float4 h1 = *(const float4*)&h_lds[kq2 * 8 + 4];
        hw_g = fmaf(h0.x, bflo(w.x), hw_g); hw_g = fmaf(h0.y, bfhi(w.x), hw_g);
        hw_g = fmaf(h0.z, bflo(w.y), hw_g); hw_g = fmaf(h0.w, bfhi(w.y), hw_g);
        hw_g = fmaf(h1.x, bflo(w.z), hw_g); hw_g = fmaf(h1.y, bfhi(w.z), hw_g);
        hw_g = fmaf(h1.z, bflo(w.w), hw_g); hw_g = fmaf(h1.w, bfhi(w.w), hw_g);
      }
      hw_g += __shfl_xor(hw_g, 1);      // both lanes hold full hw_gate[gcol]
    }
    __syncthreads();                    // B2: hw_att ready

    // ---- scores (replicated): 8 waves, wave wv covers a in [32wv, 32wv+32)
    {
      int l = tid & 63, wv = tid >> 6;
      float part = 0.f;
      #pragma unroll 8
      for (int i = 0; i < 32; ++i) {
        int a = wv * 32 + i;            // wave-uniform row -> lane-consecutive
        part = fmaf(fast_tanh(qWqT[a][l] + xa_s[a] + hw_att_s[a]),
                    wa_s[a], part);
      }
      sc_part[wv][l] = part;
    }
    __syncthreads();                    // B3: sc_part ready

    // ---- softmax (wave 0) -> al_s
    if (tid < TQL) {
      float v = 0.f;
      #pragma unroll
      for (int q = 0; q < 8; ++q) v += sc_part[q][tid];
      v = (mq > 0.f) ? v : -1e9f;
      float m = v;
      #pragma unroll
      for (int off = 32; off > 0; off >>= 1) m = fmaxf(m, __shfl_xor(m, off));
      float p = __expf(v - m);
      float su = p;
      #pragma unroll
      for (int off = 32; off > 0; off >>= 1) su += __shfl_xor(su, off);
      al_s[tid] = p * __builtin_amdgcn_rcpf(su);
    }
    __syncthreads();                    // B4: al_s ready

    // ---- pre: threads 256-511 (hold hw_g): alpha@Vl (2-way tq split)
    if (tid >= DD) {
      float dot = 0.f;
      #pragma unroll 8
      for (int i = 0; i < 32; ++i) {
        int tq = ghalf * 32 + i;
        dot = fmaf(al_s[tq], Vl_lds[tq][gcol], dot);
      }
      dot += __shfl_xor(dot, 1);
      if (ghalf == 0)
        pre_s[gcol] = hw_g + dot + xg_s[gcol] + bias_s[gcol];
    }
    __syncthreads();                    // B5: pre ready

    // ---- gates + state for own 32 h-elems; publish h slice + tag
    if (tid < 32) {
      float f  = pre_s[tid];
      float ii = pre_s[32 + tid];
      float oo = pre_s[64 + tid];
      float g  = pre_s[96 + tid];
      int m = (j << 5) + tid;
      float c0 = c_sh[tid], h0 = h_lds[m];
      float c1 = fast_sigmoid(f) * c0 + fast_sigmoid(ii) * fast_tanh(g);
      c1 = c1 * mtv + c0 * (1.f - mtv);
      float h1 = fast_sigmoid(oo) * fast_tanh(c1);
      h1 = h1 * mtv + h0 * (1.f - mtv);
      c_sh[tid] = c1;
      astoref(xch_h_b + m, h1);            // payload straight to LLC
      if (tid == 0) radd(&tags_b[j * TAGSTR]);  // release-add drains wave stores
      out[((size_t)b * TPL + t) * DD + m] = h1;
    }
    // no trailing barrier: next iteration's post-poll barrier orders h_lds reuse
  }
}

// -----------------------------------------------------------------------------
extern "C" void kernel_launch(void* const* d_in, const int* in_sizes, int n_in,
                              void* d_out, int out_size, void* d_ws, size_t ws_size,
                              hipStream_t stream) {
  const float* input_p  = (const float*)d_in[0];
  const float* mask_p   = (const float*)d_in[1];
  const float* input_q  = (const float*)d_in[2];
  const float* mask_q   = (const float*)d_in[3];
  const float* W_att_p  = (const float*)d_in[4];
  const float* W_att_q  = (const float*)d_in[5];
  const float* W_att_r  = (const float*)d_in[6];
  const float* w_att    = (const float*)d_in[7];
  const float* W_lstm   = (const float*)d_in[8];
  const float* bias_f   = (const float*)d_in[9];
  const float* bias_iog = (const float*)d_in[10];
  float* out = (float*)d_out;
  float* ws  = (float*)d_ws;
  (void)ws_size; (void)in_sizes; (void)n_in; (void)out_size;

  const size_t SZ_XPL   = (size_t)NB * TPL * NC;
  const size_t SZ_QV    = (size_t)NB * TQL * NC;
  const size_t SZ_W     = (size_t)DD * NC;
  const size_t SZ_WATT  = (size_t)32 * 256;        // uint4 per layer
  const size_t SZ_WG    = (size_t)NS * 32 * GC;    // uint4 per layer

  float* ws_xpl = ws;
  float* ws_qv  = ws_xpl + SZ_XPL;
  float* ws_wx  = ws_qv  + 2 * SZ_QV;
  float* ws_wqv = ws_wx  + 2 * SZ_W;
  float* ws_o0  = ws_wqv + 2 * SZ_W;
  uint4* ws_watt = (uint4*)(ws_o0 + (size_t)NB * TPL * DD);
  uint4* ws_wg   = ws_watt + 2 * SZ_WATT;
  float* ws_xh   = (float*)(ws_wg + 2 * SZ_WG);    // xch_h [NB][256]
  int*   ws_tag  = (int*)(ws_xh + NB * DD);        // tag_h [NB][NS] x TAGSTR

  dim3 gpack((DD * NC + 255) / 256, 2);
  pack_weights<<<gpack, 256, 0, stream>>>(W_att_p, W_att_q, W_lstm, ws_wx, ws_wqv);
  pack_whatt<<<(2 * 32 * 256) / 256, 256, 0, stream>>>(W_att_r, ws_watt);
  pack_whg<<<(2 * NS * 32 * GC) / 256, 256, 0, stream>>>(W_lstm, ws_wg);
  hipMemsetAsync(ws_tag, 0, NB * NS * TAGSTR * sizeof(int), stream);

  for (int d = 0; d < 2; ++d) {
    dim3 g(NC / 64, (NB * TQL) / 64);
    sgemm<false><<<g, 256, 0, stream>>>(input_q, ws_wqv + d * SZ_W, ws_qv + d * SZ_QV);
  }

  // layer 0
  {
    dim3 g(NC / 64, (NB * TPL) / 64);
    sgemm<true><<<g, 256, 0, stream>>>(input_p, ws_wx, ws_xpl);
    scan<<<NB * NS, 512, 0, stream>>>(ws_xpl, ws_qv, ws_watt, ws_wg,
                                      w_att, bias_f, bias_iog, mask_p, mask_q,
                                      ws_xh, ws_tag, ws_o0, 0);
  }
  // layer 1
  {
    dim3 g(NC / 64, (NB * TPL) / 64);
    sgemm<true><<<g, 256, 0, stream>>>(ws_o0, ws_wx + SZ_W, ws_xpl);
    scan<<<NB * NS, 512, 0, stream>>>(ws_xpl, ws_qv + SZ_QV, ws_watt + SZ_WATT,
                                      ws_wg + SZ_WG, w_att + DD, bias_f + DD,
                                      bias_iog + 3 * DD, mask_p, mask_q,
                                      ws_xh, ws_tag, out, TPL);
  }
}

// Round 7
// 8240.118 us; speedup vs baseline: 1.8142x; 1.1610x over previous
//
#include <hip/hip_runtime.h>
#include <hip/hip_bf16.h>

// StackedMatchLSTM on MI355X — multi-CU scan, ALL recurrent weights LDS-resident.
// B=32, TP=512, TQ=64, DP=DQ=H=AH=256, NL=2.
// Scan: 256 WGs (8 slices x 32 batches) x 512 threads. Slice j owns 32 att cols
// + 128 gate cols; its weight slices (16 KB + 64 KB bf16) are preloaded to LDS.
// Per step: poll h -> att GEMV (LDS) -> scores -> publish score partial ->
// gate GEMV (LDS, hides score flight) -> poll scores -> softmax -> pre ->
// gates -> publish h. Sync: relaxed agent payload stores + per-slice RMW tag
// (release-add / relaxed add-0 spin) — the r5/r6-proven stable primitive.

#define NB 32
#define TPL 512
#define TQL 64
#define DD 256      // DP = DQ = H = AH
#define H4 1024     // 4*H
#define NC 1280     // AH + 4H
#define NS 8        // slices per batch
#define SC 160      // xpl cols per slice = 32 att + 128 gate
#define GC 128      // gate cols per slice
#define TAGSTR 16   // ints between tags (64 B)

__device__ __forceinline__ float fast_tanh(float x) {
  float xc = fminf(fmaxf(x, -9.f), 9.f);
  float e = __expf(2.f * xc);
  return (e - 1.f) * __builtin_amdgcn_rcpf(e + 1.f);
}
__device__ __forceinline__ float fast_sigmoid(float x) {
  return __builtin_amdgcn_rcpf(1.f + __expf(-x));
}
__device__ __forceinline__ float bflo(unsigned int w) { return __uint_as_float(w << 16); }
__device__ __forceinline__ float bfhi(unsigned int w) { return __uint_as_float(w & 0xffff0000u); }
__device__ __forceinline__ unsigned int packbf(float a, float b) {
  unsigned int lo = __hip_bfloat16_raw(__float2bfloat16(a)).x;
  unsigned int hi = __hip_bfloat16_raw(__float2bfloat16(b)).x;
  return lo | (hi << 16);
}

// ---- agent-scope sync: RMW-only (executes at LLC, stale-proof) --------------
__device__ __forceinline__ float aloadf(const float* p) {
  return __hip_atomic_load(p, __ATOMIC_RELAXED, __HIP_MEMORY_SCOPE_AGENT);
}
__device__ __forceinline__ void astoref(float* p, float v) {
  __hip_atomic_store(p, v, __ATOMIC_RELAXED, __HIP_MEMORY_SCOPE_AGENT);
}
__device__ __forceinline__ void radd(int* p) {
  __hip_atomic_fetch_add(p, 1, __ATOMIC_RELEASE, __HIP_MEMORY_SCOPE_AGENT);
}
__device__ __forceinline__ void spin_ge(int* p, int tgt) {
  int guard = 0;
  while (__hip_atomic_fetch_add(p, 0, __ATOMIC_RELAXED, __HIP_MEMORY_SCOPE_AGENT) < tgt) {
    __builtin_amdgcn_s_sleep(1);
    if (++guard > (1 << 26)) break;   // bail instead of hanging the harness
  }
}

// permuted xpl cols (r3 layout): slice-major blocks of 160: 32 att | f|i|o|g x32
__device__ __forceinline__ int perm_col(int c) {
  if (c < DD) return (c >> 5) * SC + (c & 31);
  int cc = c - DD;
  int g = cc >> 8;          // 0..3 = f,i,o,g
  int m = cc & 255;         // h-elem
  return (m >> 5) * SC + 32 + (g << 5) + (m & 31);
}

// ---- weight prep ------------------------------------------------------------
__global__ __launch_bounds__(256) void pack_weights(
    const float* __restrict__ Wp, const float* __restrict__ Wq,
    const float* __restrict__ Wl,
    float* __restrict__ wx, float* __restrict__ wqv)
{
  int d = blockIdx.y;
  int idx = blockIdx.x * 256 + threadIdx.x;
  if (idx >= DD * NC) return;
  int k = idx / NC, j = idx % NC;
  int o = d * DD * NC + idx;
  const float* Wld = Wl + (size_t)d * 768 * H4;
  if (j < DD) {
    int s = d * DD * DD + k * DD + j;
    wx[o] = Wp[s]; wqv[o] = Wq[s];
  } else {
    int c = j - DD;
    wx[o]  = Wld[(size_t)k * H4 + c];
    wqv[o] = Wld[(size_t)(DD + k) * H4 + c];
  }
}

// attl[(d*8+j)*64 + kq][32 cols]: uint2 = 4 consecutive k of W_att_r[d][k][32j+col]
__global__ __launch_bounds__(256) void pack_attl(
    const float* __restrict__ Wr, uint2* __restrict__ attl)
{
  int idx = blockIdx.x * 256 + threadIdx.x;       // 2*8*64*32
  if (idx >= 2 * NS * 64 * 32) return;
  int col = idx & 31; int r = idx >> 5;
  int kq = r & 63; r >>= 6;
  int j = r & 7; int d = r >> 3;
  float v[4];
  #pragma unroll
  for (int kr = 0; kr < 4; ++kr)
    v[kr] = Wr[((size_t)d * DD + kq * 4 + kr) * DD + (j << 5) + col];
  attl[idx] = make_uint2(packbf(v[0], v[1]), packbf(v[2], v[3]));
}

// gatel[(d*8+j)*64 + kq][128 cols]: uint2 = 4 k of Wl h-part col (g,j,pos)
__global__ __launch_bounds__(256) void pack_gatel(
    const float* __restrict__ Wl, uint2* __restrict__ gatel)
{
  int idx = blockIdx.x * 256 + threadIdx.x;       // 2*8*64*128
  if (idx >= 2 * NS * 64 * GC) return;
  int col = idx & 127; int r = idx >> 7;
  int kq = r & 63; r >>= 6;
  int j = r & 7; int d = r >> 3;
  int g = col >> 5, pos = col & 31;
  float v[4];
  #pragma unroll
  for (int kr = 0; kr < 4; ++kr) {
    int k = kq * 4 + kr;
    v[kr] = Wl[((size_t)d * 768 + 512 + k) * H4 + (g << 8) + (j << 5) + pos];
  }
  gatel[idx] = make_uint2(packbf(v[0], v[1]), packbf(v[2], v[3]));
}

// ---- C[M][1280] = A[M][256] @ B[256][1280], fp32 ----------------------------
template <bool PERM>
__global__ __launch_bounds__(256) void sgemm(
    const float* __restrict__ A, const float* __restrict__ Bm,
    float* __restrict__ C)
{
  __shared__ float As[16][65];
  __shared__ float Bs[16][64];
  int tid = threadIdx.x;
  int tx = tid & 15, ty = tid >> 4;
  int col0 = blockIdx.x * 64, row0 = blockIdx.y * 64;
  float acc[4][4] = {};
  for (int kt = 0; kt < DD; kt += 16) {
    #pragma unroll
    for (int i = 0; i < 4; ++i) {
      int e = tid + i * 256;
      As[e & 15][e >> 4] = A[(size_t)(row0 + (e >> 4)) * DD + kt + (e & 15)];
      Bs[e >> 6][e & 63] = Bm[(size_t)(kt + (e >> 6)) * NC + col0 + (e & 63)];
    }
    __syncthreads();
    #pragma unroll
    for (int kk = 0; kk < 16; ++kk) {
      float a[4], bv[4];
      #pragma unroll
      for (int i = 0; i < 4; ++i) a[i] = As[kk][ty * 4 + i];
      #pragma unroll
      for (int jj = 0; jj < 4; ++jj) bv[jj] = Bs[kk][tx * 4 + jj];
      #pragma unroll
      for (int i = 0; i < 4; ++i)
        #pragma unroll
        for (int jj = 0; jj < 4; ++jj)
          acc[i][jj] = fmaf(a[i], bv[jj], acc[i][jj]);
    }
    __syncthreads();
  }
  #pragma unroll
  for (int i = 0; i < 4; ++i)
    #pragma unroll
    for (int jj = 0; jj < 4; ++jj) {
      int c = col0 + tx * 4 + jj;
      int cc = PERM ? perm_col(c) : c;
      C[(size_t)(row0 + ty * 4 + i) * NC + cc] = acc[i][jj];
    }
}

// ---- scan: 256 WGs x 512 threads, weights LDS-resident ----------------------
__global__ __launch_bounds__(512, 1) void scan(
    const float* __restrict__ xpl,    // [NB*TP][NC] permuted cols
    const float* __restrict__ qv,     // [NB*TQ][NC] plain (this layer)
    const uint2* __restrict__ attl,   // this layer's [8][64][32]
    const uint2* __restrict__ gatel,  // this layer's [8][64][128]
    const float* __restrict__ wa,     // [256]
    const float* __restrict__ bias_f,
    const float* __restrict__ bias_iog,
    const float* __restrict__ mask_p,
    const float* __restrict__ mask_q,
    float* __restrict__ xch_s,        // [NB][NS][64]
    float* __restrict__ xch_h,        // [NB][256]
    int* __restrict__ tag_s,          // [NB][NS] stride TAGSTR
    int* __restrict__ tag_h,          // [NB][NS] stride TAGSTR
    float* __restrict__ out,          // [NB*TP][256]
    int lbase)                        // layer*TPL
{
  const int bid = blockIdx.x;
  const int j = bid & 7, b = bid >> 3;
  const int tid = threadIdx.x;
  const int lane = tid & 63;

  __shared__ uint2 wg_l[64][GC];        // 64 KB gate weights
  __shared__ uint2 wat_l[64][32];       // 16 KB att weights
  __shared__ unsigned int vl_l[GC][33]; // 16.5 KB Vl bf16 pairs [col][tq/2]
  __shared__ float qT[32][65];          // 8.3 KB qWq^T (own att cols)
  __shared__ __align__(16) float h_lds[DD];
  __shared__ float xsl[SC];
  __shared__ float hw_att[32], waa[32];
  __shared__ float att_part[16][33];
  __shared__ float sc_part[8][TQL];
  __shared__ float al_s[TQL];
  __shared__ float pre_s[GC], bias_s[GC], c_sh[32];

  const float* qv_b = qv + (size_t)b * TQL * NC;
  float* xch_s_b = xch_s + b * (NS * TQL);
  float* xch_h_b = xch_h + b * DD;
  int* tags_s = tag_s + b * NS * TAGSTR;
  int* tags_h = tag_h + b * NS * TAGSTR;

  // ---- one-time preload: weights + per-batch activations into LDS
  {
    const uint2* gp = gatel + (size_t)j * 64 * GC;
    for (int i = tid; i < 64 * GC; i += 512) wg_l[i >> 7][i & 127] = gp[i];
    const uint2* ap = attl + (size_t)j * 64 * 32;
    for (int i = tid; i < 64 * 32; i += 512) wat_l[i >> 5][i & 31] = ap[i];
    for (int i = tid; i < 64 * 32; i += 512) {
      int tq = i >> 5, a = i & 31;
      qT[a][tq] = qv_b[(size_t)tq * NC + (j << 5) + a];
    }
    for (int i = tid; i < GC * 32; i += 512) {
      int col = i >> 5, tw = i & 31;
      int g = col >> 5, m = (j << 5) + (col & 31);
      float v0 = qv_b[(size_t)(2 * tw) * NC + DD + (g << 8) + m];
      float v1 = qv_b[(size_t)(2 * tw + 1) * NC + DD + (g << 8) + m];
      vl_l[col][tw] = packbf(v0, v1);
    }
    if (tid < 32) { waa[tid] = wa[(j << 5) + tid]; c_sh[tid] = 0.f; }
    if (tid < GC) {
      int g = tid >> 5, m = (j << 5) + (tid & 31);
      bias_s[tid] = (g == 0) ? bias_f[m] : bias_iog[((g - 1) << 8) + m];
    }
  }
  float mq = mask_q[b * TQL + lane];    // softmax mask, lane = tq (wave 0 uses)
  __syncthreads();

  // role indices
  const int acol = tid & 31, ak = tid >> 5;       // att: 16-way k-split
  const int stq = tid & 63, ssub = tid >> 6;      // scores: 8 subs x 4 cols
  const int gcol = tid >> 2, gq = tid & 3;        // gate/pre: 4-way k/tq split

  for (int t = 0; t < TPL; ++t) {
    const float* xrow = xpl + ((size_t)b * TPL + t) * NC + j * SC;
    float xv = (tid < SC) ? xrow[tid] : 0.f;      // in flight during poll

    // ---- wait for h[t]
    if (t > 0 && tid < NS) spin_ge(&tags_h[tid * TAGSTR], lbase + t);
    __syncthreads();                   // pollers done; prev-step LDS reads done
    if (tid < DD) h_lds[tid] = (t > 0) ? aloadf(xch_h_b + tid) : 0.f;
    if (tid < SC) xsl[tid] = xv;
    __syncthreads();                   // B1: h_lds, xsl ready

    // ---- att GEMV from LDS: 32 cols x 16-way k-split (16 k each)
    {
      float a0 = 0.f, a1 = 0.f;
      #pragma unroll
      for (int i = 0; i < 4; ++i) {
        int kq = ak * 4 + i;
        uint2 w = wat_l[kq][acol];
        float4 h0 = *(const float4*)&h_lds[kq * 4];
        a0 = fmaf(h0.x, bflo(w.x), a0); a1 = fmaf(h0.y, bfhi(w.x), a1);
        a0 = fmaf(h0.z, bflo(w.y), a0); a1 = fmaf(h0.w, bfhi(w.y), a1);
      }
      att_part[ak][acol] = a0 + a1;
    }
    __syncthreads();                   // B2
    if (tid < 32) {
      float s = 0.f;
      #pragma unroll
      for (int i = 0; i < 16; ++i) s += att_part[i][tid];
      hw_att[tid] = s;
    }
    __syncthreads();                   // B3: hw_att ready

    // ---- scores: 64 tq x 8 subs (4 a each)
    {
      float p = 0.f;
      #pragma unroll
      for (int i = 0; i < 4; ++i) {
        int a = ssub * 4 + i;
        p = fmaf(fast_tanh(qT[a][stq] + xsl[a] + hw_att[a]), waa[a], p);
      }
      sc_part[ssub][stq] = p;
    }
    __syncthreads();                   // B4
    // ---- publish score partial (wave 0), tag
    if (tid < TQL) {
      float s = 0.f;
      #pragma unroll
      for (int q = 0; q < 8; ++q) s += sc_part[q][tid];
      astoref(xch_s_b + (j << 6) + tid, s);
    }
    if (tid == 0) radd(&tags_s[j * TAGSTR]);

    // ---- gate GEMV from LDS (all 512): hides score flight
    float hwg;
    {
      float g0 = 0.f, g1 = 0.f;
      #pragma unroll
      for (int i = 0; i < 16; ++i) {
        int kq = gq * 16 + i;
        uint2 w = wg_l[kq][gcol];
        float4 h0 = *(const float4*)&h_lds[kq * 4];
        g0 = fmaf(h0.x, bflo(w.x), g0); g1 = fmaf(h0.y, bfhi(w.x), g1);
        g0 = fmaf(h0.z, bflo(w.y), g0); g1 = fmaf(h0.w, bfhi(w.y), g1);
      }
      hwg = g0 + g1;
      hwg += __shfl_xor(hwg, 1);
      hwg += __shfl_xor(hwg, 2);       // all 4 partners hold full hw_gate[gcol]
    }

    // ---- poll score tags, gather (1 load/thread), softmax
    if (tid < NS) spin_ge(&tags_s[tid * TAGSTR], lbase + t + 1);
    __syncthreads();                   // B5
    sc_part[tid >> 6][stq] = aloadf(xch_s_b + ((tid >> 6) << 6) + stq);
    __syncthreads();                   // B6
    if (tid < TQL) {
      float v = 0.f;
      #pragma unroll
      for (int q = 0; q < 8; ++q) v += sc_part[q][tid];
      v = (mq > 0.f) ? v : -1e9f;
      float m = v;
      #pragma unroll
      for (int off = 32; off > 0; off >>= 1) m = fmaxf(m, __shfl_xor(m, off));
      float p = __expf(v - m);
      float su = p;
      #pragma unroll
      for (int off = 32; off > 0; off >>= 1) su += __shfl_xor(su, off);
      al_s[tid] = p * __builtin_amdgcn_rcpf(su);
    }
    __syncthreads();                   // B7: al_s ready

    // ---- pre: alpha@Vl (4-way tq split) + hwg + x + bias
    {
      float d0 = 0.f, d1 = 0.f;
      #pragma unroll
      for (int i = 0; i < 8; ++i) {
        int tw = gq * 8 + i;
        unsigned int v = vl_l[gcol][tw];
        d0 = fmaf(al_s[2 * tw], bflo(v), d0);
        d1 = fmaf(al_s[2 * tw + 1], bfhi(v), d1);
      }
      float d = d0 + d1;
      d += __shfl_xor(d, 1);
      d += __shfl_xor(d, 2);
      if (gq == 0)
        pre_s[gcol] = hwg + d + xsl[32 + gcol] + bias_s[gcol];
    }
    __syncthreads();                   // B8: pre ready

    // ---- gates + state for own 32 h-elems; publish h slice + tag
    if (tid < 32) {
      float f  = pre_s[tid];
      float ii = pre_s[32 + tid];
      float oo = pre_s[64 + tid];
      float g  = pre_s[96 + tid];
      float mtv = mask_p[b * TPL + t];
      int m = (j << 5) + tid;
      float c0 = c_sh[tid], h0 = h_lds[m];
      float c1 = fast_sigmoid(f) * c0 + fast_sigmoid(ii) * fast_tanh(g);
      c1 = c1 * mtv + c0 * (1.f - mtv);
      float h1 = fast_sigmoid(oo) * fast_tanh(c1);
      h1 = h1 * mtv + h0 * (1.f - mtv);
      c_sh[tid] = c1;
      astoref(xch_h_b + m, h1);        // payload straight to LLC
      if (tid == 0) radd(&tags_h[j * TAGSTR]);   // release drains wave stores
      out[((size_t)b * TPL + t) * DD + m] = h1;
    }
    // no trailing barrier: next iteration's post-poll barrier orders h_lds reuse
  }
}

// -----------------------------------------------------------------------------
extern "C" void kernel_launch(void* const* d_in, const int* in_sizes, int n_in,
                              void* d_out, int out_size, void* d_ws, size_t ws_size,
                              hipStream_t stream) {
  const float* input_p  = (const float*)d_in[0];
  const float* mask_p   = (const float*)d_in[1];
  const float* input_q  = (const float*)d_in[2];
  const float* mask_q   = (const float*)d_in[3];
  const float* W_att_p  = (const float*)d_in[4];
  const float* W_att_q  = (const float*)d_in[5];
  const float* W_att_r  = (const float*)d_in[6];
  const float* w_att    = (const float*)d_in[7];
  const float* W_lstm   = (const float*)d_in[8];
  const float* bias_f   = (const float*)d_in[9];
  const float* bias_iog = (const float*)d_in[10];
  float* out = (float*)d_out;
  float* ws  = (float*)d_ws;
  (void)ws_size; (void)in_sizes; (void)n_in; (void)out_size;

  const size_t SZ_XPL  = (size_t)NB * TPL * NC;
  const size_t SZ_QV   = (size_t)NB * TQL * NC;
  const size_t SZ_W    = (size_t)DD * NC;
  const size_t SZ_ATTL = (size_t)NS * 64 * 32;    // uint2 per layer
  const size_t SZ_GATL = (size_t)NS * 64 * GC;    // uint2 per layer

  float* ws_xpl = ws;
  float* ws_qv  = ws_xpl + SZ_XPL;
  float* ws_wx  = ws_qv  + 2 * SZ_QV;
  float* ws_wqv = ws_wx  + 2 * SZ_W;
  float* ws_o0  = ws_wqv + 2 * SZ_W;
  uint2* ws_attl = (uint2*)(ws_o0 + (size_t)NB * TPL * DD);
  uint2* ws_gatl = ws_attl + 2 * SZ_ATTL;
  float* ws_xs   = (float*)(ws_gatl + 2 * SZ_GATL);  // xch_s [NB][8][64]
  float* ws_xh   = ws_xs + NB * NS * TQL;            // xch_h [NB][256]
  int*   ws_tag  = (int*)(ws_xh + NB * DD);
  int*   tag_s   = ws_tag;                           // [NB][NS] x TAGSTR
  int*   tag_h   = ws_tag + NB * NS * TAGSTR;

  dim3 gpack((DD * NC + 255) / 256, 2);
  pack_weights<<<gpack, 256, 0, stream>>>(W_att_p, W_att_q, W_lstm, ws_wx, ws_wqv);
  pack_attl<<<(2 * NS * 64 * 32 + 255) / 256, 256, 0, stream>>>(W_att_r, ws_attl);
  pack_gatel<<<(2 * NS * 64 * GC + 255) / 256, 256, 0, stream>>>(W_lstm, ws_gatl);
  hipMemsetAsync(ws_tag, 0, 2 * NB * NS * TAGSTR * sizeof(int), stream);

  for (int d = 0; d < 2; ++d) {
    dim3 g(NC / 64, (NB * TQL) / 64);
    sgemm<false><<<g, 256, 0, stream>>>(input_q, ws_wqv + d * SZ_W, ws_qv + d * SZ_QV);
  }

  // layer 0
  {
    dim3 g(NC / 64, (NB * TPL) / 64);
    sgemm<true><<<g, 256, 0, stream>>>(input_p, ws_wx, ws_xpl);
    scan<<<NB * NS, 512, 0, stream>>>(ws_xpl, ws_qv, ws_attl, ws_gatl,
                                      w_att, bias_f, bias_iog, mask_p, mask_q,
                                      ws_xs, ws_xh, tag_s, tag_h, ws_o0, 0);
  }
  // layer 1
  {
    dim3 g(NC / 64, (NB * TPL) / 64);
    sgemm<true><<<g, 256, 0, stream>>>(ws_o0, ws_wx + SZ_W, ws_xpl);
    scan<<<NB * NS, 512, 0, stream>>>(ws_xpl, ws_qv + SZ_QV, ws_attl + SZ_ATTL,
                                      ws_gatl + SZ_GATL, w_att + DD, bias_f + DD,
                                      bias_iog + 3 * DD, mask_p, mask_q,
                                      ws_xs, ws_xh, tag_s, tag_h, out, TPL);
  }
}